// Round 1
// baseline (2631.261 us; speedup 1.0000x reference)
//
#include <hip/hip_runtime.h>
#include <hip/hip_bf16.h>

typedef __bf16 bf16x8 __attribute__((ext_vector_type(8)));
typedef __bf16 bf16x4 __attribute__((ext_vector_type(4)));
typedef float  f32x4  __attribute__((ext_vector_type(4)));

#define TM       64
#define NTHREADS 512
#define XS       392            // X/H row stride (bf16 elems): 384+8 pad -> 784 B, 16B-aligned, bank-offset 4
#define YS       520            // Y row stride: 512+8 pad -> 1040 B, 16B-aligned, bank-offset 4
#define SM_H     66560          // after Y region (64*520*2)
#define SM_GATE  116736         // after H region (64*392*2)
#define SM_IDX   116992
#define SM_TOTAL 117504

// ws layout (bf16 elems): W1t[384][384] | W2t[512][384] (cols 1..512 of W2) | W3t[128][512]
#define W1T_ELEMS 147456
#define W2T_ELEMS 196608
#define W3T_ELEMS 65536

__global__ void prep_weights(const float* __restrict__ W1, const float* __restrict__ W2,
                             const float* __restrict__ W3, __bf16* __restrict__ ws) {
    int i = blockIdx.x * blockDim.x + threadIdx.x;   // 800*512 = 409600 exact
    if (i < W1T_ELEMS) {
        int n = i / 384, k = i - n * 384;
        ws[i] = (__bf16)W1[k * 384 + n];
    } else if (i < W1T_ELEMS + W2T_ELEMS) {
        int j = i - W1T_ELEMS;
        int n = j / 384, k = j - n * 384;
        ws[i] = (__bf16)W2[k * 513 + n + 1];         // skip gate column 0
    } else {
        int j = i - (W1T_ELEMS + W2T_ELEMS);
        int n = j / 512, k = j - n * 512;
        ws[i] = (__bf16)W3[k * 128 + n];
    }
}

__global__ __launch_bounds__(NTHREADS, 2) void fused_edge_mlp(
    const float* __restrict__ vc, const float* __restrict__ ve1, const float* __restrict__ ve2,
    const int* __restrict__ src, const int* __restrict__ dst,
    const float* __restrict__ b1, const float* __restrict__ W2, const float* __restrict__ b2,
    const float* __restrict__ b3,
    const __bf16* __restrict__ W1t, const __bf16* __restrict__ W2t, const __bf16* __restrict__ W3t,
    float* __restrict__ out)
{
    extern __shared__ char smem[];
    __bf16* sX    = (__bf16*)smem;               // [64][392], dead after phase A
    __bf16* sY    = (__bf16*)smem;               // [64][520], overlays X
    __bf16* sH    = (__bf16*)(smem + SM_H);      // [64][392]
    float*  sGate = (float*)(smem + SM_GATE);    // [64]
    int*    sIdx  = (int*)(smem + SM_IDX);       // [128]

    const int tid  = threadIdx.x;
    const int wave = tid >> 6;
    const int lane = tid & 63;
    const int quad = lane >> 4;
    const int l16  = lane & 15;
    const int e0   = blockIdx.x * TM;

    if (tid < TM) {
        sIdx[tid]      = src[e0 + tid];
        sIdx[TM + tid] = dst[e0 + tid];
    }
    __syncthreads();

    // ---- gather + fp32->bf16 convert X tile into LDS ----
    for (int q = tid; q < TM * 96; q += NTHREADS) {
        int row = q / 96, seg = q - row * 96;
        float4 v;
        if (seg < 32)      v = ((const float4*)(vc + sIdx[row] * 128))[seg];
        else if (seg < 64) v = ((const float4*)(vc + sIdx[TM + row] * 128))[seg - 32];
        else if (seg < 80) v = ((const float4*)(ve1 + (e0 + row) * 64))[seg - 64];
        else               v = ((const float4*)(ve2 + (e0 + row) * 64))[seg - 80];
        bf16x4 t = { (__bf16)v.x, (__bf16)v.y, (__bf16)v.z, (__bf16)v.w };
        *(bf16x4*)(sX + row * XS + seg * 4) = t;
    }
    __syncthreads();

    // ---- phase A: H = relu(X @ W1 + b1)   N=384, wave handles 3 n-tiles ----
    {
        f32x4 acc[3][4] = {};
        const int nbase = wave * 48;
        for (int kt = 0; kt < 12; ++kt) {
            const int k0 = kt * 32 + quad * 8;
            bf16x8 a[4];
            #pragma unroll
            for (int mt = 0; mt < 4; ++mt)
                a[mt] = *(const bf16x8*)(sX + (mt * 16 + l16) * XS + k0);
            #pragma unroll
            for (int nt = 0; nt < 3; ++nt) {
                bf16x8 b = *(const bf16x8*)(W1t + (nbase + nt * 16 + l16) * 384 + k0);
                #pragma unroll
                for (int mt = 0; mt < 4; ++mt)
                    acc[nt][mt] = __builtin_amdgcn_mfma_f32_16x16x32_bf16(a[mt], b, acc[nt][mt], 0, 0, 0);
            }
        }
        #pragma unroll
        for (int nt = 0; nt < 3; ++nt) {
            const int col  = nbase + nt * 16 + l16;
            const float bias = b1[col];
            #pragma unroll
            for (int mt = 0; mt < 4; ++mt)
                #pragma unroll
                for (int j = 0; j < 4; ++j) {
                    float v = acc[nt][mt][j] + bias;
                    sH[(mt * 16 + quad * 4 + j) * XS + col] = (__bf16)(v > 0.f ? v : 0.f);
                }
        }
    }
    __syncthreads();

    // ---- gate: y0 = H . W2[:,0] + b2[0]; sigmoid. 8 threads per row ----
    {
        const int row = tid >> 3, part = tid & 7;
        const int kk = part * 48;
        float s = 0.f;
        #pragma unroll 8
        for (int k = 0; k < 48; ++k)
            s += (float)sH[row * XS + kk + k] * W2[(kk + k) * 513];
        s += __shfl_down(s, 4, 8);
        s += __shfl_down(s, 2, 8);
        s += __shfl_down(s, 1, 8);
        if (part == 0) sGate[row] = 1.f / (1.f + __expf(-(s + b2[0])));
    }

    // ---- phase B: Ytail = H @ W2[:,1:] + b2[1:]   N=512, wave handles 4 n-tiles ----
    {
        f32x4 acc[4][4] = {};
        for (int kt = 0; kt < 12; ++kt) {
            const int k0 = kt * 32 + quad * 8;
            bf16x8 a[4];
            #pragma unroll
            for (int mt = 0; mt < 4; ++mt)
                a[mt] = *(const bf16x8*)(sH + (mt * 16 + l16) * XS + k0);
            #pragma unroll
            for (int nt = 0; nt < 4; ++nt) {
                bf16x8 b = *(const bf16x8*)(W2t + ((wave * 4 + nt) * 16 + l16) * 384 + k0);
                #pragma unroll
                for (int mt = 0; mt < 4; ++mt)
                    acc[nt][mt] = __builtin_amdgcn_mfma_f32_16x16x32_bf16(a[mt], b, acc[nt][mt], 0, 0, 0);
            }
        }
        #pragma unroll
        for (int nt = 0; nt < 4; ++nt) {
            const int col  = (wave * 4 + nt) * 16 + l16;     // 0..511 == y column col+1
            const float bias = b2[col + 1];
            #pragma unroll
            for (int mt = 0; mt < 4; ++mt)
                #pragma unroll
                for (int j = 0; j < 4; ++j)
                    sY[(mt * 16 + quad * 4 + j) * YS + col] = (__bf16)(acc[nt][mt][j] + bias);
        }
    }
    __syncthreads();

    // ---- phase C: out = gate * (Ytail @ W3) + b3   N=128, 1 n-tile per wave ----
    {
        f32x4 acc[4] = {};
        for (int kt = 0; kt < 16; ++kt) {
            const int k0 = kt * 32 + quad * 8;
            bf16x8 b = *(const bf16x8*)(W3t + (wave * 16 + l16) * 512 + k0);
            #pragma unroll
            for (int mt = 0; mt < 4; ++mt) {
                bf16x8 a = *(const bf16x8*)(sY + (mt * 16 + l16) * YS + k0);
                acc[mt] = __builtin_amdgcn_mfma_f32_16x16x32_bf16(a, b, acc[mt], 0, 0, 0);
            }
        }
        const int col  = wave * 16 + l16;
        const float bias = b3[col];
        #pragma unroll
        for (int mt = 0; mt < 4; ++mt)
            #pragma unroll
            for (int j = 0; j < 4; ++j) {
                const int row = mt * 16 + quad * 4 + j;
                out[(e0 + row) * 128 + col] = sGate[row] * acc[mt][j] + bias;
            }
    }
}

extern "C" void kernel_launch(void* const* d_in, const int* in_sizes, int n_in,
                              void* d_out, int out_size, void* d_ws, size_t ws_size,
                              hipStream_t stream) {
    const float* vc  = (const float*)d_in[0];
    const float* ve1 = (const float*)d_in[1];
    const float* ve2 = (const float*)d_in[2];
    const int*   src = (const int*)d_in[3];
    const int*   dst = (const int*)d_in[4];
    const float* W1  = (const float*)d_in[5];
    const float* b1  = (const float*)d_in[6];
    const float* W2  = (const float*)d_in[7];
    const float* b2  = (const float*)d_in[8];
    const float* W3  = (const float*)d_in[9];
    const float* b3  = (const float*)d_in[10];
    float* out = (float*)d_out;

    __bf16* W1t = (__bf16*)d_ws;
    __bf16* W2t = W1t + W1T_ELEMS;
    __bf16* W3t = W2t + W2T_ELEMS;

    prep_weights<<<800, 512, 0, stream>>>(W1, W2, W3, W1t);

    hipFuncSetAttribute((const void*)fused_edge_mlp,
                        hipFuncAttributeMaxDynamicSharedMemorySize, SM_TOTAL);
    fused_edge_mlp<<<12500, NTHREADS, SM_TOTAL, stream>>>(
        vc, ve1, ve2, src, dst, b1, W2, b2, b3, W1t, W2t, W3t, out);
}